// Round 11
// baseline (908.331 us; speedup 1.0000x reference)
//
#include <hip/hip_runtime.h>

// ---------------------------------------------------------------------------
// Round 10: N-split 2-block co-residency (phase overlap across blocks).
//  R9 budget: MFMA 48us, HBM 46us, L2 44us, VALU ~38us, dur 190us -> phase
//  serialization at 1 block/CU is the cost. Split each 64-row tile's columns
//  across TWO 512-thread blocks (8 waves; wave w -> within-gate col-tile
//  half*8+w). Per-thread acc stays 64, regs <=128 -> 16 waves/CU = 2 blocks
//  co-resident (LDS 2x64KB). Block A's MFMA overlaps block B's stage/epilogue.
//  Kept from R9: K-split h-first, dotS/dotO precompute, R4-exact epilogue,
//  short-lived blocks (wp stays L2-hot).
// ---------------------------------------------------------------------------

#define D_DIM 256
#define NNODE 32
#define NEDGE 992
#define EDGE_ROWS (128 * NEDGE)   // 126976
#define NODE_ROWS (128 * NNODE)   // 4096
#define BM 64
#define XH_OFF 0                   // x half: bytes [0,512) within a 1KB row
#define HH_OFF 512                 // h half: bytes [512,1024)

typedef _Float16 half8 __attribute__((ext_vector_type(8)));
typedef __attribute__((ext_vector_type(4))) float f32x4;

__device__ __forceinline__ float sigf(float x) { return 1.0f / (1.0f + __expf(-x)); }
__device__ __forceinline__ float tanh_fast(float x) { return 2.0f / (1.0f + __expf(-2.0f * x)) - 1.0f; }
__device__ __forceinline__ float dot4(float4 a, float4 b) { return a.x*b.x + a.y*b.y + a.z*b.z + a.w*b.w; }

// Pack Wc[512][768] (rows 0-255 = WihT, 256-511 = WhhT) into MFMA B-fragment
// order, f16: ph[((ct*16+ks)*64+l)*8+j] = f16(Wc[ks*32+(l>>4)*8+j][ct*16+(l&15)])
__global__ __launch_bounds__(64) void pack_w(const float* __restrict__ Wih,
                                             const float* __restrict__ Whh,
                                             _Float16* __restrict__ ph) {
  const int ct = blockIdx.x;   // 0..47
  const int ks = blockIdx.y;   // 0..15
  const int l = threadIdx.x;   // 0..63
  const int col = ct * 16 + (l & 15);
  const int kb = ks * 32 + (l >> 4) * 8;
  const float* src = (kb < 256) ? (Wih + col * 256 + kb) : (Whh + col * 256 + (kb - 256));
  half8 v;
  #pragma unroll
  for (int j = 0; j < 8; ++j) v[j] = (_Float16)src[j];
  *(half8*)(ph + ((ct * 16 + ks) * 64 + l) * 8) = v;
}

template <bool INIT, bool GATES>
__global__ __launch_bounds__(512, 4) void gru_mfma(
    const float* __restrict__ xsrc, const float* __restrict__ nhid,
    float* __restrict__ h, const _Float16* __restrict__ wp,
    const float* __restrict__ bih, const float* __restrict__ bhh,
    const float* __restrict__ wesb, const float* __restrict__ weob,
    const float* __restrict__ dotS, const float* __restrict__ dotO) {
  constexpr int RSTR = INIT ? 512 : 1024;   // LDS row stride (bytes)
  __shared__ __align__(16) unsigned char lds[BM * RSTR];

  const int t = threadIdx.x;
  const int half = blockIdx.x & 1;          // which col-half of the tile
  const int rb = (blockIdx.x >> 1) * BM;
  const int sr16 = t >> 4;       // staging: 16 threads per row, 32 rows/pass
  const int skc = t & 15;
  const int w = t >> 6;          // wave 0..7
  const int ct = half * 8 + w;   // within-gate col-tile 0..15
  const int l = t & 63;
  const int lq = l >> 4;
  const int lr = l & 15;
  const int swm = (lr & 7) << 4;
  const int swz = (sr16 & 7) << 4;   // (row&7) == (sr16&7) since pass offset is 32

  float gsv[2] = {1.f, 1.f}, gov[2] = {0.f, 0.f};

  if constexpr (!INIT) {
    // ---- stage h rows (2 passes of 32 rows), consume fully ----
    #pragma unroll
    for (int p = 0; p < 2; ++p) {
      const int row = p * 32 + sr16;
      const int rowg = rb + row;
      float4 pre[4];
      #pragma unroll
      for (int i = 0; i < 4; ++i)
        pre[i] = *(const float4*)(h + rowg * D_DIM + (i >> 1) * 128 + skc * 8 + (i & 1) * 4);
      #pragma unroll
      for (int c = 0; c < 2; ++c) {
        half8 hh8;
        const float* f1 = (const float*)&pre[c * 2];
        #pragma unroll
        for (int j = 0; j < 8; ++j) hh8[j] = (_Float16)f1[j];
        *(half8*)(&lds[(row * RSTR + HH_OFF + c * 256 + skc * 16) ^ swz]) = hh8;
      }
      if constexpr (GATES) {
        const int b = rowg / NEDGE;
        const int e = rowg - b * NEDGE;
        const int si = e / 31;
        const int m = e - si * 31;
        const int ob = (m < si) ? m : (m + 1);
        float pS = 0.f, pO = 0.f;
        #pragma unroll
        for (int i = 0; i < 4; ++i) {
          const int k0 = (i >> 1) * 128 + skc * 8 + (i & 1) * 4;
          pS += dot4(pre[i], *(const float4*)(wesb + k0));
          pO += dot4(pre[i], *(const float4*)(weob + k0));
        }
        #pragma unroll
        for (int mm = 1; mm < 16; mm <<= 1) {
          pS += __shfl_xor(pS, mm, 16);
          pO += __shfl_xor(pO, mm, 16);
        }
        gsv[p] = sigf(dotS[b * NNODE + si] + pS);
        gov[p] = sigf(dotO[b * NNODE + ob] + pO);
      }
    }
  }

  const f32x4 zz = {0.f, 0.f, 0.f, 0.f};
  f32x4 acc_r[4] = {zz, zz, zz, zz};
  f32x4 acc_z[4] = {zz, zz, zz, zz};
  f32x4 acc_nx[4] = {zz, zz, zz, zz};
  f32x4 acc_nh[4] = {zz, zz, zz, zz};

  auto KS = [&](int hoff, int ksgl, int ksg, f32x4 (&accn)[4]) {
    half8 ah[4];
    #pragma unroll
    for (int rf = 0; rf < 4; ++rf)
      ah[rf] = *(const half8*)(&lds[((rf * 16 + lr) * RSTR + hoff + ksgl * 64 + lq * 16) ^ swm]);
    const half8 br_ = *(const half8*)(wp + (((0 * 16 + ct) * 16 + ksg) * 64 + l) * 8);
    const half8 bz_ = *(const half8*)(wp + (((1 * 16 + ct) * 16 + ksg) * 64 + l) * 8);
    const half8 bn_ = *(const half8*)(wp + (((2 * 16 + ct) * 16 + ksg) * 64 + l) * 8);
    #pragma unroll
    for (int rf = 0; rf < 4; ++rf)
      acc_r[rf] = __builtin_amdgcn_mfma_f32_16x16x32_f16(ah[rf], br_, acc_r[rf], 0, 0, 0);
    #pragma unroll
    for (int rf = 0; rf < 4; ++rf)
      acc_z[rf] = __builtin_amdgcn_mfma_f32_16x16x32_f16(ah[rf], bz_, acc_z[rf], 0, 0, 0);
    #pragma unroll
    for (int rf = 0; rf < 4; ++rf)
      accn[rf] = __builtin_amdgcn_mfma_f32_16x16x32_f16(ah[rf], bn_, accn[rf], 0, 0, 0);
  };

  if constexpr (!INIT) {
    __syncthreads();
    // 96 h-half MFMAs
    #pragma unroll
    for (int ksgl = 0; ksgl < 8; ++ksgl) KS(HH_OFF, ksgl, 8 + ksgl, acc_nh);
  }

  // ---- combine: load x rows (L2-hot), consume immediately (2 passes) ----
  #pragma unroll
  for (int p = 0; p < 2; ++p) {
    const int row = p * 32 + sr16;
    const int rowg = rb + row;
    const float* pxa;
    const float* pxb = nullptr;
    if constexpr (GATES) {
      const int b = rowg / NEDGE;
      const int e = rowg - b * NEDGE;
      const int si = e / 31;
      const int m = e - si * 31;
      const int ob = (m < si) ? m : (m + 1);
      pxa = nhid + (b * NNODE + si) * D_DIM;
      pxb = nhid + (b * NNODE + ob) * D_DIM;
    } else {
      pxa = xsrc + rowg * D_DIM;
    }
    const float gs = gsv[p], go = gov[p];
    #pragma unroll
    for (int c = 0; c < 2; ++c) {
      half8 hx;
      #pragma unroll
      for (int pq = 0; pq < 2; ++pq) {
        const int k0 = c * 128 + skc * 8 + pq * 4;
        const float4 a = *(const float4*)(pxa + k0);
        float4 v = a;
        if constexpr (GATES) {
          const float4 b4 = *(const float4*)(pxb + k0);
          v.x = gs * a.x + go * b4.x; v.y = gs * a.y + go * b4.y;
          v.z = gs * a.z + go * b4.z; v.w = gs * a.w + go * b4.w;
        }
        hx[pq * 4 + 0] = (_Float16)v.x; hx[pq * 4 + 1] = (_Float16)v.y;
        hx[pq * 4 + 2] = (_Float16)v.z; hx[pq * 4 + 3] = (_Float16)v.w;
      }
      *(half8*)(&lds[(row * RSTR + XH_OFF + c * 256 + skc * 16) ^ swz]) = hx;
    }
  }
  __syncthreads();

  // 96 x-half MFMAs
  #pragma unroll
  for (int ksgl = 0; ksgl < 8; ++ksgl) KS(XH_OFF, ksgl, ksgl, acc_nx);

  // ---- epilogue: per-rf immediate compute + store (R4-exact) ----
  const int col = ct * 16 + lr;
  const float br = bih[col] + bhh[col];
  const float bz = bih[256 + col] + bhh[256 + col];
  const float bnx = bih[512 + col];
  const float bnh = bhh[512 + col];
  #pragma unroll
  for (int rf = 0; rf < 4; ++rf) {
    const int row0 = rb + rf * 16 + lq * 4;
    #pragma unroll
    for (int q = 0; q < 4; ++q) {
      const float r = sigf(acc_r[rf][q] + br);
      const float z = sigf(acc_z[rf][q] + bz);
      const float n = tanh_fast(acc_nx[rf][q] + bnx + r * (acc_nh[rf][q] + bnh));
      float hv = 0.0f;
      if constexpr (!INIT) hv = h[(row0 + q) * D_DIM + col];
      h[(row0 + q) * D_DIM + col] = (1.0f - z) * n + z * hv;
    }
  }
}

// per node row: dotA = nh.wnp[0:256], dotS = nh.wes[0:256], dotO = nh.weo[0:256]
__global__ __launch_bounds__(256) void dot3_kernel(
    const float* __restrict__ nh, const float* __restrict__ wnp,
    const float* __restrict__ wes, const float* __restrict__ weo,
    float* __restrict__ dA, float* __restrict__ dS, float* __restrict__ dO) {
  const int r = blockIdx.x * 4 + (threadIdx.x >> 6);
  const int l = threadIdx.x & 63;
  const float4 v = ((const float4*)(nh + r * D_DIM))[l];
  float p1 = dot4(v, ((const float4*)wnp)[l]);
  float p2 = dot4(v, ((const float4*)wes)[l]);
  float p3 = dot4(v, ((const float4*)weo)[l]);
  #pragma unroll
  for (int mm = 32; mm > 0; mm >>= 1) {
    p1 += __shfl_xor(p1, mm, 64);
    p2 += __shfl_xor(p2, mm, 64);
    p3 += __shfl_xor(p3, mm, 64);
  }
  if (l == 0) { dA[r] = p1; dS[r] = p2; dO[r] = p3; }
}

// node_msg[b,n] = sum over 62 incident edges of gN*eh,
// gN = sig(dotA[b,sub] + eh . w_node_pool[256:512]) computed inline.
__global__ __launch_bounds__(256) void node_msg_kernel(
    const float* __restrict__ eh, const float* __restrict__ wnp,
    const float* __restrict__ dotA, float* __restrict__ nmsg) {
  __shared__ float sh[3][256];
  const int nr = blockIdx.x;  // 0..4095
  const int b = nr >> 5;
  const int n = nr & 31;
  const int wv = threadIdx.x >> 6;
  const int l = threadIdx.x & 63;
  const int base = b * NEDGE;
  const float4 w1b = ((const float4*)(wnp + 256))[l];

  float4 acc = {0.f, 0.f, 0.f, 0.f};
  for (int k = wv; k < 62; k += 4) {
    int e, sub;
    if (k < 31) {             // out-edge (n -> *)
      e = base + n * 31 + k;
      sub = n;
    } else {                  // in-edge (i -> n)
      int i = k - 31;
      const int ip = (i < n) ? i : (i + 1);
      e = base + ip * 31 + ((n < ip) ? n : (n - 1));
      sub = ip;
    }
    const float4 ev = ((const float4*)(eh + e * D_DIM))[l];
    float p = dot4(ev, w1b);
    #pragma unroll
    for (int mm = 32; mm > 0; mm >>= 1) p += __shfl_xor(p, mm, 64);
    const float gN = sigf(dotA[b * NNODE + sub] + p);
    acc.x += gN * ev.x; acc.y += gN * ev.y; acc.z += gN * ev.z; acc.w += gN * ev.w;
  }
  if (wv > 0) *(float4*)(&sh[wv - 1][l * 4]) = acc;
  __syncthreads();
  if (wv == 0) {
    #pragma unroll
    for (int v = 0; v < 3; ++v) {
      const float4 o = *(const float4*)(&sh[v][l * 4]);
      acc.x += o.x; acc.y += o.y; acc.z += o.z; acc.w += o.w;
    }
    *(float4*)(nmsg + nr * D_DIM + l * 4) = acc;
  }
}

extern "C" void kernel_launch(void* const* d_in, const int* in_sizes, int n_in,
                              void* d_out, int out_size, void* d_ws, size_t ws_size,
                              hipStream_t stream) {
  const float* node_latents = (const float*)d_in[0];
  const float* edge_latents = (const float*)d_in[1];
  const float* node_Wih = (const float*)d_in[2];
  const float* node_Whh = (const float*)d_in[3];
  const float* node_bih = (const float*)d_in[4];
  const float* node_bhh = (const float*)d_in[5];
  const float* edge_Wih = (const float*)d_in[6];
  const float* edge_Whh = (const float*)d_in[7];
  const float* edge_bih = (const float*)d_in[8];
  const float* edge_bhh = (const float*)d_in[9];
  const float* w_node_pool = (const float*)d_in[10];
  const float* w_edge_sub = (const float*)d_in[11];
  const float* w_edge_obj = (const float*)d_in[12];

  float* nh = (float*)d_out;
  float* eh = (float*)d_out + NODE_ROWS * D_DIM;

  const int WPLANE = 48 * 16 * 64 * 8;  // 393216 f16 = 768KB
  _Float16* ph_n = (_Float16*)d_ws;
  _Float16* ph_e = ph_n + WPLANE;
  float* fw = (float*)(ph_e + WPLANE);
  float* dotA = fw; fw += NODE_ROWS;
  float* dotS = fw; fw += NODE_ROWS;
  float* dotO = fw; fw += NODE_ROWS;
  float* node_msg = fw; fw += NODE_ROWS * D_DIM;  // total ~5.7 MB

  dim3 pg(48, 16);
  pack_w<<<pg, 64, 0, stream>>>(node_Wih, node_Whh, ph_n);
  pack_w<<<pg, 64, 0, stream>>>(edge_Wih, edge_Whh, ph_e);

  const int EGRID = (EDGE_ROWS / BM) * 2;  // 3968 (2 col-half blocks per tile)
  const int NGRID = (NODE_ROWS / BM) * 2;  // 128

  gru_mfma<true, false><<<NGRID, 512, 0, stream>>>(
      node_latents, nullptr, nh, ph_n, node_bih, node_bhh,
      nullptr, nullptr, nullptr, nullptr);
  gru_mfma<true, false><<<EGRID, 512, 0, stream>>>(
      edge_latents, nullptr, eh, ph_e, edge_bih, edge_bhh,
      nullptr, nullptr, nullptr, nullptr);

  for (int it = 0; it < 3; ++it) {
    dot3_kernel<<<NODE_ROWS / 4, 256, 0, stream>>>(nh, w_node_pool, w_edge_sub,
                                                   w_edge_obj, dotA, dotS, dotO);
    node_msg_kernel<<<NODE_ROWS, 256, 0, stream>>>(eh, w_node_pool, dotA, node_msg);
    gru_mfma<false, true><<<EGRID, 512, 0, stream>>>(
        nullptr, nh, eh, ph_e, edge_bih, edge_bhh,
        w_edge_sub + 256, w_edge_obj + 256, dotS, dotO);
    gru_mfma<false, false><<<NGRID, 512, 0, stream>>>(
        node_msg, nullptr, nh, ph_n, node_bih, node_bhh,
        nullptr, nullptr, nullptr, nullptr);
  }
}

// Round 12
// 744.008 us; speedup vs baseline: 1.2209x; 1.2209x over previous
//
#include <hip/hip_runtime.h>

// ---------------------------------------------------------------------------
// Round 11: hoist the edge x-GEMM to node granularity (NW = nh @ edge_WihT).
//  x = gS*nh[sub]+gO*nh[obj]  =>  x@WihT = gS*NW[sub]+gO*NW[obj]  (exact).
//  NW: 4096x768 f16 GEMM (31x less work than the edge GEMM it replaces).
//  Edge iter kernel (MODE 2): stage eh -> f16 LDS + gate dots; gather 2 NW
//  rows/edge, combine with packed-f16 FMA into gi-LDS [64][776]; ONE barrier;
//  96 h-MFMAs (wp h-half only -> L2 stream halved); epilogue reads gi (LDS)
//  + hv (global, L1/L2-hot from staging).
//  MODE 0 (init GRU) / MODE 1 (node iter, R9 K-split) unchanged from R9.
//  Spill discipline: all staging loads consumed in <=32-reg chunks.
// ---------------------------------------------------------------------------

#define D_DIM 256
#define NNODE 32
#define NEDGE 992
#define EDGE_ROWS (128 * NEDGE)   // 126976
#define NODE_ROWS (128 * NNODE)   // 4096
#define BM 64
#define XH_OFF 0                  // MODE1: x half [0,512) of 1KB row
#define HH_OFF 512                // MODE1: h half [512,1024)
#define GI_OFF 32768              // MODE2: gi region after the 32KB h region
#define GI_STR 776                // gi row stride in f16 words (768 + 8 pad)

typedef _Float16 half8 __attribute__((ext_vector_type(8)));
typedef __attribute__((ext_vector_type(4))) float f32x4;

__device__ __forceinline__ float sigf(float x) { return 1.0f / (1.0f + __expf(-x)); }
__device__ __forceinline__ float tanh_fast(float x) { return 2.0f / (1.0f + __expf(-2.0f * x)) - 1.0f; }
__device__ __forceinline__ float dot4(float4 a, float4 b) { return a.x*b.x + a.y*b.y + a.z*b.z + a.w*b.w; }

// Pack Wc[512][768] (rows 0-255 = WihT, 256-511 = WhhT) into MFMA B-fragment
// order, f16: ph[((g*16+ct)*16+ks)*64+l)*8+j]
__global__ __launch_bounds__(64) void pack_w(const float* __restrict__ Wih,
                                             const float* __restrict__ Whh,
                                             _Float16* __restrict__ ph) {
  const int ct = blockIdx.x;   // 0..47
  const int ks = blockIdx.y;   // 0..15
  const int l = threadIdx.x;   // 0..63
  const int col = ct * 16 + (l & 15);
  const int kb = ks * 32 + (l >> 4) * 8;
  const float* src = (kb < 256) ? (Wih + col * 256 + kb) : (Whh + col * 256 + (kb - 256));
  half8 v;
  #pragma unroll
  for (int j = 0; j < 8; ++j) v[j] = (_Float16)src[j];
  *(half8*)(ph + ((ct * 16 + ks) * 64 + l) * 8) = v;
}

// MODE 0: init GRU (x only, h=0).  MODE 1: node iter GRU (R9 K-split).
// MODE 2: edge iter (h-GEMM + NW-combined gi).  MODE 3: NW = x @ WihT (raw f16 out).
template <int MODE>
__global__ __launch_bounds__(1024, 4) void gru_mfma(
    const float* __restrict__ xsrc, float* __restrict__ h,
    const _Float16* __restrict__ wp,
    const float* __restrict__ bih, const float* __restrict__ bhh,
    const float* __restrict__ wesb, const float* __restrict__ weob,
    const float* __restrict__ dotS, const float* __restrict__ dotO,
    _Float16* __restrict__ nw) {
  constexpr int RSTR = (MODE == 1) ? 1024 : 512;
  constexpr int LDSB = (MODE == 1) ? 65536 : (MODE == 2 ? 32768 + BM * GI_STR * 2 : 32768);
  __shared__ __align__(16) unsigned char lds[LDSB];

  const int t = threadIdx.x;
  const int rb = blockIdx.x * BM;
  const int srow = t >> 4;       // staging: 16 threads per row
  const int skc = t & 15;
  const int w = t >> 6;          // compute: wave -> within-gate col-tile
  const int l = t & 63;
  const int lq = l >> 4;
  const int lr = l & 15;
  const int swm = (lr & 7) << 4;
  const int swz = (srow & 7) << 4;
  const int rowg = rb + srow;

  if constexpr (MODE == 2) {
    // ---- stage eh row: f16 LDS + gate dots; then NW gather -> gi LDS ----
    const int b = rowg / NEDGE;
    const int e = rowg - b * NEDGE;
    const int si = e / 31;
    const int m = e - si * 31;
    const int ob = (m < si) ? m : (m + 1);

    float4 pre[4];
    #pragma unroll
    for (int i = 0; i < 4; ++i)
      pre[i] = *(const float4*)(h + rowg * D_DIM + (i >> 1) * 128 + skc * 8 + (i & 1) * 4);
    #pragma unroll
    for (int c = 0; c < 2; ++c) {
      half8 hh8;
      const float* f1 = (const float*)&pre[c * 2];
      #pragma unroll
      for (int j = 0; j < 8; ++j) hh8[j] = (_Float16)f1[j];
      *(half8*)(&lds[(srow * 512 + c * 256 + skc * 16) ^ swz]) = hh8;
    }
    float pS = 0.f, pO = 0.f;
    #pragma unroll
    for (int i = 0; i < 4; ++i) {
      const int k0 = (i >> 1) * 128 + skc * 8 + (i & 1) * 4;
      pS += dot4(pre[i], *(const float4*)(wesb + k0));
      pO += dot4(pre[i], *(const float4*)(weob + k0));
    }
    #pragma unroll
    for (int mm = 1; mm < 16; mm <<= 1) {
      pS += __shfl_xor(pS, mm, 16);
      pO += __shfl_xor(pO, mm, 16);
    }
    const float gs = sigf(dotS[b * NNODE + si] + pS);
    const float go = sigf(dotO[b * NNODE + ob] + pO);
    const _Float16 gsh = (_Float16)gs, goh = (_Float16)go;
    const _Float16* ns = nw + (b * NNODE + si) * 768;
    const _Float16* no_ = nw + (b * NNODE + ob) * 768;
    _Float16* giw = (_Float16*)(lds + GI_OFF) + srow * GI_STR;
    #pragma unroll
    for (int j = 0; j < 6; ++j) {          // cols skc*8 + j*128 (conflict-free)
      const int c0 = skc * 8 + j * 128;
      const half8 a = *(const half8*)(ns + c0);
      const half8 bb = *(const half8*)(no_ + c0);
      half8 g;
      #pragma unroll
      for (int k = 0; k < 8; ++k) g[k] = gsh * a[k] + goh * bb[k];
      *(half8*)(giw + c0) = g;
    }
  } else if constexpr (MODE != 1) {
    // MODE 0 / 3: stage x rows up-front
    #pragma unroll
    for (int c = 0; c < 2; ++c) {
      half8 hx;
      #pragma unroll
      for (int pq = 0; pq < 2; ++pq) {
        const float4 a = *(const float4*)(xsrc + rowg * D_DIM + c * 128 + skc * 8 + pq * 4);
        hx[pq * 4 + 0] = (_Float16)a.x; hx[pq * 4 + 1] = (_Float16)a.y;
        hx[pq * 4 + 2] = (_Float16)a.z; hx[pq * 4 + 3] = (_Float16)a.w;
      }
      *(half8*)(&lds[(srow * 512 + c * 256 + skc * 16) ^ swz]) = hx;
    }
  } else {
    // MODE 1 stage1: h rows (f16), consumed fully
    float4 pre[4];
    #pragma unroll
    for (int i = 0; i < 4; ++i)
      pre[i] = *(const float4*)(h + rowg * D_DIM + (i >> 1) * 128 + skc * 8 + (i & 1) * 4);
    #pragma unroll
    for (int c = 0; c < 2; ++c) {
      half8 hh8;
      const float* f1 = (const float*)&pre[c * 2];
      #pragma unroll
      for (int j = 0; j < 8; ++j) hh8[j] = (_Float16)f1[j];
      *(half8*)(&lds[(srow * RSTR + HH_OFF + c * 256 + skc * 16) ^ swz]) = hh8;
    }
  }

  const f32x4 zz = {0.f, 0.f, 0.f, 0.f};
  f32x4 acc_r[4] = {zz, zz, zz, zz};
  f32x4 acc_z[4] = {zz, zz, zz, zz};
  f32x4 acc_nx[4] = {zz, zz, zz, zz};
  f32x4 acc_nh[4] = {zz, zz, zz, zz};

  auto KS = [&](int hoff, int ksgl, int ksg, f32x4 (&accn)[4]) {
    half8 ah[4];
    #pragma unroll
    for (int rf = 0; rf < 4; ++rf)
      ah[rf] = *(const half8*)(&lds[((rf * 16 + lr) * RSTR + hoff + ksgl * 64 + lq * 16) ^ swm]);
    const half8 br_ = *(const half8*)(wp + (((0 * 16 + w) * 16 + ksg) * 64 + l) * 8);
    const half8 bz_ = *(const half8*)(wp + (((1 * 16 + w) * 16 + ksg) * 64 + l) * 8);
    const half8 bn_ = *(const half8*)(wp + (((2 * 16 + w) * 16 + ksg) * 64 + l) * 8);
    #pragma unroll
    for (int rf = 0; rf < 4; ++rf)
      acc_r[rf] = __builtin_amdgcn_mfma_f32_16x16x32_f16(ah[rf], br_, acc_r[rf], 0, 0, 0);
    #pragma unroll
    for (int rf = 0; rf < 4; ++rf)
      acc_z[rf] = __builtin_amdgcn_mfma_f32_16x16x32_f16(ah[rf], bz_, acc_z[rf], 0, 0, 0);
    #pragma unroll
    for (int rf = 0; rf < 4; ++rf)
      accn[rf] = __builtin_amdgcn_mfma_f32_16x16x32_f16(ah[rf], bn_, accn[rf], 0, 0, 0);
  };

  __syncthreads();

  if constexpr (MODE == 0 || MODE == 3) {
    #pragma unroll
    for (int ksgl = 0; ksgl < 8; ++ksgl) KS(0, ksgl, ksgl, acc_nx);
  } else if constexpr (MODE == 2) {
    #pragma unroll
    for (int ksgl = 0; ksgl < 8; ++ksgl) KS(0, ksgl, 8 + ksgl, acc_nh);
  } else {
    // MODE 1: 96 h-MFMAs, then stage x (L2-hot node_msg), then 96 x-MFMAs
    #pragma unroll
    for (int ksgl = 0; ksgl < 8; ++ksgl) KS(HH_OFF, ksgl, 8 + ksgl, acc_nh);
    #pragma unroll
    for (int c = 0; c < 2; ++c) {
      half8 hx;
      #pragma unroll
      for (int pq = 0; pq < 2; ++pq) {
        const float4 a = *(const float4*)(xsrc + rowg * D_DIM + c * 128 + skc * 8 + pq * 4);
        hx[pq * 4 + 0] = (_Float16)a.x; hx[pq * 4 + 1] = (_Float16)a.y;
        hx[pq * 4 + 2] = (_Float16)a.z; hx[pq * 4 + 3] = (_Float16)a.w;
      }
      *(half8*)(&lds[(srow * RSTR + XH_OFF + c * 256 + skc * 16) ^ swz]) = hx;
    }
    __syncthreads();
    #pragma unroll
    for (int ksgl = 0; ksgl < 8; ++ksgl) KS(XH_OFF, ksgl, ksgl, acc_nx);
  }

  // ---------------- epilogue ----------------
  const int col = w * 16 + lr;
  if constexpr (MODE == 3) {
    #pragma unroll
    for (int rf = 0; rf < 4; ++rf) {
      #pragma unroll
      for (int q = 0; q < 4; ++q) {
        const int rowl = rf * 16 + lq * 4 + q;
        _Float16* np = nw + (rb + rowl) * 768 + col;
        np[0]   = (_Float16)acc_r[rf][q];
        np[256] = (_Float16)acc_z[rf][q];
        np[512] = (_Float16)acc_nx[rf][q];
      }
    }
    return;
  }
  const float br = bih[col] + bhh[col];
  const float bz = bih[256 + col] + bhh[256 + col];
  const float bnx = bih[512 + col];
  const float bnh = bhh[512 + col];
  if constexpr (MODE == 2) {
    const _Float16* gir = (const _Float16*)(lds + GI_OFF);
    #pragma unroll
    for (int rf = 0; rf < 4; ++rf) {
      #pragma unroll
      for (int q = 0; q < 4; ++q) {
        const int rowl = rf * 16 + lq * 4 + q;
        const _Float16* gp = gir + rowl * GI_STR + col;
        const float r = sigf(acc_r[rf][q] + (float)gp[0] + br);
        const float z = sigf(acc_z[rf][q] + (float)gp[256] + bz);
        const float n = tanh_fast((float)gp[512] + bnx + r * (acc_nh[rf][q] + bnh));
        const float hv = h[(rb + rowl) * D_DIM + col];
        h[(rb + rowl) * D_DIM + col] = (1.0f - z) * n + z * hv;
      }
    }
  } else {
    #pragma unroll
    for (int rf = 0; rf < 4; ++rf) {
      #pragma unroll
      for (int q = 0; q < 4; ++q) {
        const int rowl = rf * 16 + lq * 4 + q;
        const float r = sigf(acc_r[rf][q] + br);
        const float z = sigf(acc_z[rf][q] + bz);
        const float n = tanh_fast(acc_nx[rf][q] + bnx + r * (acc_nh[rf][q] + bnh));
        float hv = 0.0f;
        if constexpr (MODE == 1) hv = h[(rb + rowl) * D_DIM + col];
        h[(rb + rowl) * D_DIM + col] = (1.0f - z) * n + z * hv;
      }
    }
  }
}

// per node row: dotA = nh.wnp[0:256], dotS = nh.wes[0:256], dotO = nh.weo[0:256]
__global__ __launch_bounds__(256) void dot3_kernel(
    const float* __restrict__ nh, const float* __restrict__ wnp,
    const float* __restrict__ wes, const float* __restrict__ weo,
    float* __restrict__ dA, float* __restrict__ dS, float* __restrict__ dO) {
  const int r = blockIdx.x * 4 + (threadIdx.x >> 6);
  const int l = threadIdx.x & 63;
  const float4 v = ((const float4*)(nh + r * D_DIM))[l];
  float p1 = dot4(v, ((const float4*)wnp)[l]);
  float p2 = dot4(v, ((const float4*)wes)[l]);
  float p3 = dot4(v, ((const float4*)weo)[l]);
  #pragma unroll
  for (int mm = 32; mm > 0; mm >>= 1) {
    p1 += __shfl_xor(p1, mm, 64);
    p2 += __shfl_xor(p2, mm, 64);
    p3 += __shfl_xor(p3, mm, 64);
  }
  if (l == 0) { dA[r] = p1; dS[r] = p2; dO[r] = p3; }
}

// node_msg[b,n] = sum over 62 incident edges of gN*eh,
// gN = sig(dotA[b,sub] + eh . w_node_pool[256:512]) computed inline.
__global__ __launch_bounds__(256) void node_msg_kernel(
    const float* __restrict__ eh, const float* __restrict__ wnp,
    const float* __restrict__ dotA, float* __restrict__ nmsg) {
  __shared__ float sh[3][256];
  const int nr = blockIdx.x;  // 0..4095
  const int b = nr >> 5;
  const int n = nr & 31;
  const int wv = threadIdx.x >> 6;
  const int l = threadIdx.x & 63;
  const int base = b * NEDGE;
  const float4 w1b = ((const float4*)(wnp + 256))[l];

  float4 acc = {0.f, 0.f, 0.f, 0.f};
  for (int k = wv; k < 62; k += 4) {
    int e, sub;
    if (k < 31) {
      e = base + n * 31 + k;
      sub = n;
    } else {
      int i = k - 31;
      const int ip = (i < n) ? i : (i + 1);
      e = base + ip * 31 + ((n < ip) ? n : (n - 1));
      sub = ip;
    }
    const float4 ev = ((const float4*)(eh + e * D_DIM))[l];
    float p = dot4(ev, w1b);
    #pragma unroll
    for (int mm = 32; mm > 0; mm >>= 1) p += __shfl_xor(p, mm, 64);
    const float gN = sigf(dotA[b * NNODE + sub] + p);
    acc.x += gN * ev.x; acc.y += gN * ev.y; acc.z += gN * ev.z; acc.w += gN * ev.w;
  }
  if (wv > 0) *(float4*)(&sh[wv - 1][l * 4]) = acc;
  __syncthreads();
  if (wv == 0) {
    #pragma unroll
    for (int v = 0; v < 3; ++v) {
      const float4 o = *(const float4*)(&sh[v][l * 4]);
      acc.x += o.x; acc.y += o.y; acc.z += o.z; acc.w += o.w;
    }
    *(float4*)(nmsg + nr * D_DIM + l * 4) = acc;
  }
}

extern "C" void kernel_launch(void* const* d_in, const int* in_sizes, int n_in,
                              void* d_out, int out_size, void* d_ws, size_t ws_size,
                              hipStream_t stream) {
  const float* node_latents = (const float*)d_in[0];
  const float* edge_latents = (const float*)d_in[1];
  const float* node_Wih = (const float*)d_in[2];
  const float* node_Whh = (const float*)d_in[3];
  const float* node_bih = (const float*)d_in[4];
  const float* node_bhh = (const float*)d_in[5];
  const float* edge_Wih = (const float*)d_in[6];
  const float* edge_Whh = (const float*)d_in[7];
  const float* edge_bih = (const float*)d_in[8];
  const float* edge_bhh = (const float*)d_in[9];
  const float* w_node_pool = (const float*)d_in[10];
  const float* w_edge_sub = (const float*)d_in[11];
  const float* w_edge_obj = (const float*)d_in[12];

  float* nh = (float*)d_out;
  float* eh = (float*)d_out + NODE_ROWS * D_DIM;

  const int WPLANE = 48 * 16 * 64 * 8;  // 393216 f16 = 768KB
  _Float16* ph_n = (_Float16*)d_ws;
  _Float16* ph_e = ph_n + WPLANE;
  _Float16* NW = ph_e + WPLANE;                    // 4096 x 768 f16 = 6 MB
  float* fw = (float*)(NW + NODE_ROWS * 768);
  float* dotA = fw; fw += NODE_ROWS;
  float* dotS = fw; fw += NODE_ROWS;
  float* dotO = fw; fw += NODE_ROWS;
  float* node_msg = fw; fw += NODE_ROWS * D_DIM;   // total ~11.6 MB

  dim3 pg(48, 16);
  pack_w<<<pg, 64, 0, stream>>>(node_Wih, node_Whh, ph_n);
  pack_w<<<pg, 64, 0, stream>>>(edge_Wih, edge_Whh, ph_e);

  gru_mfma<0><<<NODE_ROWS / BM, 1024, 0, stream>>>(
      node_latents, nh, ph_n, node_bih, node_bhh,
      nullptr, nullptr, nullptr, nullptr, nullptr);
  gru_mfma<0><<<EDGE_ROWS / BM, 1024, 0, stream>>>(
      edge_latents, eh, ph_e, edge_bih, edge_bhh,
      nullptr, nullptr, nullptr, nullptr, nullptr);

  for (int it = 0; it < 3; ++it) {
    dot3_kernel<<<NODE_ROWS / 4, 256, 0, stream>>>(nh, w_node_pool, w_edge_sub,
                                                   w_edge_obj, dotA, dotS, dotO);
    gru_mfma<3><<<NODE_ROWS / BM, 1024, 0, stream>>>(
        nh, nullptr, ph_e, nullptr, nullptr,
        nullptr, nullptr, nullptr, nullptr, NW);
    node_msg_kernel<<<NODE_ROWS, 256, 0, stream>>>(eh, w_node_pool, dotA, node_msg);
    gru_mfma<2><<<EDGE_ROWS / BM, 1024, 0, stream>>>(
        nullptr, eh, ph_e, edge_bih, edge_bhh,
        w_edge_sub + 256, w_edge_obj + 256, dotS, dotO, NW);
    gru_mfma<1><<<NODE_ROWS / BM, 1024, 0, stream>>>(
        node_msg, nh, ph_n, node_bih, node_bhh,
        nullptr, nullptr, nullptr, nullptr, nullptr);
  }
}